// Round 4
// baseline (707.624 us; speedup 1.0000x reference)
//
#include <hip/hip_runtime.h>

#define C_FEAT 128
#define C_EDGE 32
#define K1 288
#define ZS 136   // LDS row stride in shorts (128 + 8 pad)

typedef __attribute__((ext_vector_type(8))) short bf16x8;
typedef __attribute__((ext_vector_type(4))) float f32x4;

__device__ __forceinline__ short f2bf(float x) {
    union { float f; unsigned u; } v; v.f = x;
    unsigned r = v.u + 0x7fffu + ((v.u >> 16) & 1u);   // RTN-even
    return (short)(r >> 16);
}
__device__ __forceinline__ float b2f(short s) {
    union { float f; unsigned u; } v; v.u = ((unsigned)(unsigned short)s) << 16;
    return v.f;
}
__device__ __forceinline__ bf16x8 cvt8(float4 a, float4 b) {
    bf16x8 r;
    r[0] = f2bf(a.x); r[1] = f2bf(a.y); r[2] = f2bf(a.z); r[3] = f2bf(a.w);
    r[4] = f2bf(b.x); r[5] = f2bf(b.y); r[6] = f2bf(b.z); r[7] = f2bf(b.w);
    return r;
}

// ---------------- weight packing ----------------
// B-fragment layout: wp[((k>>3)*F + f)*8 + (k&7)] -> 8 consecutive k for fixed
// f is one coalesced 16B load per lane.
__global__ void prep_w2(const float* __restrict__ We1, const float* __restrict__ We2,
                        short* __restrict__ w1abp, short* __restrict__ w1cp,
                        short* __restrict__ w2p) {
    int idx = blockIdx.x * 256 + threadIdx.x;
    if (idx < 128 * 256) {              // [W1a | W1b]: K=128, F=256
        int k = idx >> 8, f = idx & 255;
        float v = (f < 128) ? We1[k * 128 + f] : We1[(128 + k) * 128 + (f - 128)];
        w1abp[(((k >> 3) * 256 + f) << 3) + (k & 7)] = f2bf(v);
    }
    if (idx < 32 * 128) {               // W1c: K=32, F=128
        int k = idx >> 7, f = idx & 127;
        w1cp[(((k >> 3) * 128 + f) << 3) + (k & 7)] = f2bf(We1[(256 + k) * 128 + f]);
    }
    if (idx < 128 * 128) {              // We2
        int k = idx >> 7, f = idx & 127;
        w2p[(((k >> 3) * 128 + f) << 3) + (k & 7)] = f2bf(We2[k * 128 + f]);
    }
}

// ---------------- counting sort by ej (hist zeroed via memsetAsync) -------
__global__ void k_hist(const int* __restrict__ ej, int* __restrict__ hist, int E) {
    int e = blockIdx.x * 256 + threadIdx.x;
    if (e < E) atomicAdd(&hist[ej[e]], 1);
}
__global__ void k_red(const int* __restrict__ hist, int* __restrict__ part, int N) {
    __shared__ int s[512];
    int t = threadIdx.x, i = blockIdx.x * 512 + t;
    s[t] = i < N ? hist[i] : 0;
    __syncthreads();
    for (int o = 256; o > 0; o >>= 1) {
        if (t < o) s[t] += s[t + o];
        __syncthreads();
    }
    if (t == 0) part[blockIdx.x] = s[0];
}
__global__ void k_scanpart(int* __restrict__ part, int nb) {
    if (threadIdx.x == 0 && blockIdx.x == 0) {
        int a = 0;
        for (int i = 0; i < nb; ++i) { int v = part[i]; part[i] = a; a += v; }
    }
}
// exclusive scan -> woff (mutated by k_perm) and rstart (preserved CSR offsets)
__global__ void k_scanblk(const int* __restrict__ hist, const int* __restrict__ part,
                          int* __restrict__ woff, int* __restrict__ rstart, int N) {
    __shared__ int s[512];
    int t = threadIdx.x, i = blockIdx.x * 512 + t;
    int v = i < N ? hist[i] : 0;
    s[t] = v;
    __syncthreads();
    for (int o = 1; o < 512; o <<= 1) {
        int x = (t >= o) ? s[t - o] : 0;
        __syncthreads();
        s[t] += x;
        __syncthreads();
    }
    if (i < N) {
        int ex = part[blockIdx.x] + s[t] - v;
        woff[i] = ex;
        rstart[i] = ex;
    }
}
// permute edges into ej-sorted order; fuse ea gather+bf16 convert.
__global__ void k_perm(const int* __restrict__ ei, const int* __restrict__ ej,
                       const float* __restrict__ ea, int* __restrict__ woff,
                       int* __restrict__ ei_s, int* __restrict__ ej_s,
                       short* __restrict__ ea_s, int E) {
    int e = blockIdx.x * 256 + threadIdx.x;
    if (e < E) {
        int t = ej[e];
        int pos = atomicAdd(&woff[t], 1);
        ei_s[pos] = ei[e];
        ej_s[pos] = t;
        const float4* src = (const float4*)(ea + (size_t)e * C_EDGE);
        short* dst = ea_s + (size_t)pos * C_EDGE;
#pragma unroll
        for (int c = 0; c < 4; ++c) {
            float4 a0 = src[2 * c], a1 = src[2 * c + 1];
            bf16x8 v = cvt8(a0, a1);
            *(bf16x8*)(dst + c * 8) = v;
        }
    }
}

// ---------------- Xab = h @ [W1a|W1b]  (N x 256, bf16) ----------------
__global__ __launch_bounds__(256) void gemm1(const float* __restrict__ h,
                                             const short* __restrict__ w1abp,
                                             short* __restrict__ Xab, int N) {
    const int tid = threadIdx.x, wave = tid >> 6, lane = tid & 63;
    const int l15 = lane & 15, q = lane >> 4;
    const int nbase = blockIdx.x * 64 + wave * 16;
    const int nr = nbase + l15;
    const int nrc = nr < N ? nr : N - 1;
    f32x4 acc[16];
#pragma unroll
    for (int nt = 0; nt < 16; ++nt) acc[nt] = (f32x4){0.f, 0.f, 0.f, 0.f};
#pragma unroll
    for (int c = 0; c < 4; ++c) {
        const float* asrc = h + (size_t)nrc * C_FEAT + c * 32 + q * 8;
        float4 a0 = ((const float4*)asrc)[0];
        float4 a1 = ((const float4*)asrc)[1];
        bf16x8 af = cvt8(a0, a1);
        const short* bb = w1abp + ((c * 4 + q) * 256) * 8;
#pragma unroll
        for (int nt = 0; nt < 16; ++nt) {
            bf16x8 bf = *(const bf16x8*)(bb + (nt * 16 + l15) * 8);
            acc[nt] = __builtin_amdgcn_mfma_f32_16x16x32_bf16(af, bf, acc[nt], 0, 0, 0);
        }
    }
#pragma unroll
    for (int rr = 0; rr < 4; ++rr) {
        int n = nbase + q * 4 + rr;
        if (n < N) {
#pragma unroll
            for (int nt = 0; nt < 16; ++nt) {
                Xab[(size_t)n * 256 + nt * 16 + l15] = f2bf(acc[nt][rr]);
            }
        }
    }
}

// ---- node-owner edge pass: wave owns 16 nodes; processes its sorted edge
// range in 32-edge MFMA chunks; segmented-sums m rows in VALU; writes each
// node row ONCE with plain RMW stores. Zero atomics, zero barriers. ----
__global__ __launch_bounds__(256) void edge_pass(const short* __restrict__ Xab,
                                                 const short* __restrict__ ea_s,
                                                 const int* __restrict__ ei_s,
                                                 const int* __restrict__ ej_s,
                                                 const short* __restrict__ w1cp,
                                                 const float* __restrict__ be1,
                                                 const short* __restrict__ w2p,
                                                 const float* __restrict__ be2,
                                                 const int* __restrict__ rstart,
                                                 float* out, int E, int N) {
    __shared__ short Zs[4][32 * ZS];   // per-wave slice: Z then M (reused)
    const int tid = threadIdx.x, wave = tid >> 6, lane = tid & 63;
    const int l15 = lane & 15, q = lane >> 4;
    const int group = blockIdx.x * 4 + wave;
    const int n0 = group * 16;
    if (n0 >= N) return;
    const int nend = (n0 + 16 < N) ? n0 + 16 : N;
    int s   = rstart[n0];
    int end = (nend == N) ? E : rstart[nend];
    s   = __builtin_amdgcn_readfirstlane(s);
    end = __builtin_amdgcn_readfirstlane(end);

    short* zw = &Zs[wave][0];
    const int f0 = lane * 2;          // this lane's f-pair for the VALU sum

    float be1v[8], b2v[8];
#pragma unroll
    for (int nt = 0; nt < 8; ++nt) {
        be1v[nt] = be1[nt * 16 + l15];
        b2v[nt]  = be2[nt * 16 + l15];
    }

    int cur = -1;
    float sum0 = 0.f, sum1 = 0.f;

    for (int cb = s; cb < end; cb += 32) {
        int eL[2], ni2[2], nj2[2];
#pragma unroll
        for (int t = 0; t < 2; ++t) {
            int e = cb + t * 16 + l15;
            eL[t] = e < E ? e : E - 1;
            ni2[t] = ei_s[eL[t]];
            nj2[t] = ej_s[eL[t]];
        }

        // ---- z = ea @ W1c + be1 -> wave-local LDS (A-layout for layer 2) ----
#pragma unroll
        for (int t = 0; t < 2; ++t) {
            bf16x8 af = *(const bf16x8*)(ea_s + (size_t)eL[t] * C_EDGE + q * 8);
#pragma unroll
            for (int nt = 0; nt < 8; ++nt) {
                bf16x8 bf = *(const bf16x8*)(w1cp + ((q * C_FEAT + nt * 16 + l15) << 3));
                f32x4 ac = __builtin_amdgcn_mfma_f32_16x16x32_bf16(
                    af, bf, (f32x4){0.f, 0.f, 0.f, 0.f}, 0, 0, 0);
                int f = nt * 16 + l15;
#pragma unroll
                for (int r = 0; r < 4; ++r)
                    zw[(t * 16 + q * 4 + r) * ZS + f] = f2bf(ac[r] + be1v[nt]);
            }
        }

        // ---- layer 2: relu(Xa[ei]+Xb[ej]+z) @ We2 ----
        f32x4 acc[2][8];
#pragma unroll
        for (int t = 0; t < 2; ++t)
#pragma unroll
            for (int nt = 0; nt < 8; ++nt) acc[t][nt] = (f32x4){0.f, 0.f, 0.f, 0.f};

#pragma unroll
        for (int c = 0; c < 4; ++c) {
            bf16x8 bfr[8];
            const short* bb = w2p + ((c * 4 + q) * C_FEAT) * 8;
#pragma unroll
            for (int nt = 0; nt < 8; ++nt)
                bfr[nt] = *(const bf16x8*)(bb + (nt * 16 + l15) * 8);
#pragma unroll
            for (int t = 0; t < 2; ++t) {
                bf16x8 xa = *(const bf16x8*)(Xab + (size_t)ni2[t] * 256 + c * 32 + q * 8);
                bf16x8 xb = *(const bf16x8*)(Xab + (size_t)nj2[t] * 256 + 128 + c * 32 + q * 8);
                bf16x8 zz = *(const bf16x8*)(&zw[(t * 16 + l15) * ZS + c * 32 + q * 8]);
                bf16x8 af;
#pragma unroll
                for (int j = 0; j < 8; ++j) {
                    float z = b2f(xa[j]) + b2f(xb[j]) + b2f(zz[j]);
                    af[j] = f2bf(z > 0.f ? z : 0.f);
                }
#pragma unroll
                for (int nt = 0; nt < 8; ++nt)
                    acc[t][nt] = __builtin_amdgcn_mfma_f32_16x16x32_bf16(af, bfr[nt],
                                                                         acc[t][nt], 0, 0, 0);
            }
        }

        // ---- m rows (+be2) -> LDS, C-layout row = edge-in-chunk ----
#pragma unroll
        for (int t = 0; t < 2; ++t)
#pragma unroll
            for (int nt = 0; nt < 8; ++nt) {
                int f = nt * 16 + l15;
#pragma unroll
                for (int r = 0; r < 4; ++r)
                    zw[(t * 16 + q * 4 + r) * ZS + f] = f2bf(acc[t][nt][r] + b2v[nt]);
            }

        // ---- segmented sum over this chunk's edges (wave-uniform branches) ----
        int kmax = end - cb; if (kmax > 32) kmax = 32;
        for (int k = 0; k < kmax; ++k) {
            int n = __builtin_amdgcn_readfirstlane(ej_s[cb + k]);
            if (n != cur) {
                if (cur >= 0) {
                    float* p = out + (size_t)cur * C_FEAT + f0;
                    float b0 = p[0], b1 = p[1];
                    p[0] = b0 + sum0; p[1] = b1 + sum1;
                }
                cur = n; sum0 = 0.f; sum1 = 0.f;
            }
            unsigned mv = *(const unsigned*)(&zw[k * ZS + f0]);
            sum0 += b2f((short)(mv & 0xffff));
            sum1 += b2f((short)(mv >> 16));
        }
    }
    if (cur >= 0) {
        float* p = out + (size_t)cur * C_FEAT + f0;
        float b0 = p[0], b1 = p[1];
        p[0] = b0 + sum0; p[1] = b1 + sum1;
    }
}

// ---------------- elementwise helpers ----------------
__global__ void copy_f4(const float4* __restrict__ s, float4* __restrict__ d, int n4) {
    int i = blockIdx.x * 256 + threadIdx.x;
    if (i < n4) d[i] = s[i];
}
__global__ void bias_copy(const float4* __restrict__ s, const float* __restrict__ bias,
                          float4* __restrict__ d, int n4) {
    int i = blockIdx.x * 256 + threadIdx.x;
    if (i < n4) {
        float4 v = s[i];
        float4 b = ((const float4*)bias)[i & 31];
        d[i] = make_float4(v.x + b.x, v.y + b.y, v.z + b.z, v.w + b.w);
    }
}

// ================= round-1 fallback path (known-good) =================
__global__ void prep_w_r1(const float* __restrict__ W1, const float* __restrict__ W2,
                          short* __restrict__ w1p, short* __restrict__ w2p) {
    int idx = blockIdx.x * 256 + threadIdx.x;
    if (idx < K1 * C_FEAT) {
        int k = idx >> 7, f = idx & 127;
        w1p[(((k >> 3) * C_FEAT + f) << 3) + (k & 7)] = f2bf(W1[idx]);
    }
    if (idx < C_FEAT * C_FEAT) {
        int k = idx >> 7, f = idx & 127;
        w2p[(((k >> 3) * C_FEAT + f) << 3) + (k & 7)] = f2bf(W2[idx]);
    }
}
__global__ __launch_bounds__(256) void edge_mlp_r1(
    const float* __restrict__ h, float* __restrict__ hdst,
    const int* __restrict__ ei, const int* __restrict__ ej,
    const float* __restrict__ ea,
    const short* __restrict__ w1p, const float* __restrict__ be1,
    const short* __restrict__ w2p, const float* __restrict__ be2, int E) {
    __shared__ short Hs[64][136];
    const int tid = threadIdx.x, wave = tid >> 6, lane = tid & 63;
    const int l15 = lane & 15, q = lane >> 4;
    const int ewave = blockIdx.x * 64 + wave * 16;
    const int eg = ewave + l15;
    const int egc = eg < E ? eg : E - 1;
    const int ni = ei[egc], nj = ej[egc];
    f32x4 acc[8];
#pragma unroll
    for (int nt = 0; nt < 8; ++nt) acc[nt] = (f32x4){0.f, 0.f, 0.f, 0.f};
#pragma unroll
    for (int c = 0; c < 9; ++c) {
        const float* asrc;
        if (c < 4)      asrc = h + (size_t)ni * C_FEAT + c * 32 + q * 8;
        else if (c < 8) asrc = h + (size_t)nj * C_FEAT + (c - 4) * 32 + q * 8;
        else            asrc = ea + (size_t)egc * C_EDGE + q * 8;
        float4 a0 = ((const float4*)asrc)[0];
        float4 a1 = ((const float4*)asrc)[1];
        bf16x8 af = cvt8(a0, a1);
        const short* bb = w1p + ((c * 4 + q) * C_FEAT) * 8;
#pragma unroll
        for (int nt = 0; nt < 8; ++nt) {
            bf16x8 bf = *(const bf16x8*)(bb + (nt * 16 + l15) * 8);
            acc[nt] = __builtin_amdgcn_mfma_f32_16x16x32_bf16(af, bf, acc[nt], 0, 0, 0);
        }
    }
#pragma unroll
    for (int nt = 0; nt < 8; ++nt) {
        int f = nt * 16 + l15;
        float b = be1[f];
#pragma unroll
        for (int r = 0; r < 4; ++r) {
            float v = acc[nt][r] + b;
            Hs[wave * 16 + q * 4 + r][f] = f2bf(v > 0.f ? v : 0.f);
        }
    }
    __syncthreads();
    f32x4 acc2[8];
#pragma unroll
    for (int nt = 0; nt < 8; ++nt) acc2[nt] = (f32x4){0.f, 0.f, 0.f, 0.f};
#pragma unroll
    for (int c = 0; c < 4; ++c) {
        bf16x8 af = *(const bf16x8*)(&Hs[wave * 16 + l15][c * 32 + q * 8]);
        const short* bb = w2p + ((c * 4 + q) * C_FEAT) * 8;
#pragma unroll
        for (int nt = 0; nt < 8; ++nt) {
            bf16x8 bf = *(const bf16x8*)(bb + (nt * 16 + l15) * 8);
            acc2[nt] = __builtin_amdgcn_mfma_f32_16x16x32_bf16(af, bf, acc2[nt], 0, 0, 0);
        }
    }
    float b2v[8];
#pragma unroll
    for (int nt = 0; nt < 8; ++nt) b2v[nt] = be2[nt * 16 + l15];
#pragma unroll
    for (int r = 0; r < 4; ++r) {
        int e = ewave + q * 4 + r;
        if (e < E) {
            int tn = ej[e];
            float* dst = hdst + (size_t)tn * C_FEAT;
#pragma unroll
            for (int nt = 0; nt < 8; ++nt)
                unsafeAtomicAdd(dst + nt * 16 + l15, acc2[nt][r] + b2v[nt]);
        }
    }
}

static inline size_t al256(size_t x) { return (x + 255) & ~(size_t)255; }

extern "C" void kernel_launch(void* const* d_in, const int* in_sizes, int n_in,
                              void* d_out, int out_size, void* d_ws, size_t ws_size,
                              hipStream_t stream) {
    const float* x    = (const float*)d_in[0];
    const int*   eidx = (const int*)  d_in[1];
    const float* ea   = (const float*)d_in[2];
    const float* We1  = (const float*)d_in[3];
    const float* be1  = (const float*)d_in[4];
    const float* We2  = (const float*)d_in[5];
    const float* be2  = (const float*)d_in[6];
    const float* bias = (const float*)d_in[7];
    float* out = (float*)d_out;

    const int E = in_sizes[1] / 2;
    const int N = in_sizes[0] / C_FEAT;
    const int* ei = eidx;
    const int* ej = eidx + E;

    const int n4 = N * C_FEAT / 4;
    const int cb = (n4 + 255) / 256;
    const int ngroups = (N + 15) / 16;
    const int nblocks = (ngroups + 3) / 4;

    // ---- workspace layout ----
    size_t off = 0;
    size_t o_w1abp = off; off = al256(off + (size_t)128 * 256 * 2);
    size_t o_w1cp  = off; off = al256(off + (size_t)32 * 128 * 2);
    size_t o_w2p   = off; off = al256(off + (size_t)128 * 128 * 2);
    size_t o_hist  = off; off = al256(off + (size_t)N * 4);
    size_t o_part  = off; off = al256(off + (size_t)4096);
    size_t o_woff  = off; off = al256(off + (size_t)N * 4);
    size_t o_rst   = off; off = al256(off + (size_t)N * 4);
    size_t o_eis   = off; off = al256(off + (size_t)E * 4);
    size_t o_ejs   = off; off = al256(off + (size_t)E * 4);
    size_t o_eas   = off; off = al256(off + (size_t)E * C_EDGE * 2);
    size_t o_xab   = off; off = al256(off + (size_t)N * 256 * 2);
    const size_t need = off;

    if (ws_size >= need) {
        char* ws = (char*)d_ws;
        short* w1abp = (short*)(ws + o_w1abp);
        short* w1cp  = (short*)(ws + o_w1cp);
        short* w2p   = (short*)(ws + o_w2p);
        int* hist    = (int*)(ws + o_hist);
        int* part    = (int*)(ws + o_part);
        int* woff    = (int*)(ws + o_woff);
        int* rstart  = (int*)(ws + o_rst);
        int* ei_s    = (int*)(ws + o_eis);
        int* ej_s    = (int*)(ws + o_ejs);
        short* ea_s  = (short*)(ws + o_eas);
        short* Xab   = (short*)(ws + o_xab);

        const int nbScan = (N + 511) / 512;

        prep_w2<<<128, 256, 0, stream>>>(We1, We2, w1abp, w1cp, w2p);
        // counting sort by ej (+ fused ea permute/convert) + CSR offsets
        hipMemsetAsync(hist, 0, (size_t)N * 4, stream);
        k_hist<<<(E + 255) / 256, 256, 0, stream>>>(ej, hist, E);
        k_red<<<nbScan, 512, 0, stream>>>(hist, part, N);
        k_scanpart<<<1, 64, 0, stream>>>(part, nbScan);
        k_scanblk<<<nbScan, 512, 0, stream>>>(hist, part, woff, rstart, N);
        k_perm<<<(E + 255) / 256, 256, 0, stream>>>(ei, ej, ea, woff, ei_s, ej_s, ea_s, E);

        // step 1: out = x + scatter(m1)
        gemm1<<<(N + 63) / 64, 256, 0, stream>>>(x, w1abp, Xab, N);
        copy_f4<<<cb, 256, 0, stream>>>((const float4*)x, (float4*)out, n4);
        edge_pass<<<nblocks, 256, 0, stream>>>(Xab, ea_s, ei_s, ej_s, w1cp, be1,
                                               w2p, be2, rstart, out, E, N);
        // step 2: out = h1 + bias + scatter(m2)
        gemm1<<<(N + 63) / 64, 256, 0, stream>>>(out, w1abp, Xab, N);
        bias_copy<<<cb, 256, 0, stream>>>((const float4*)out, bias, (float4*)out, n4);
        edge_pass<<<nblocks, 256, 0, stream>>>(Xab, ea_s, ei_s, ej_s, w1cp, be1,
                                               w2p, be2, rstart, out, E, N);
    } else {
        // round-1 known-good fallback
        const int eb = (E + 63) / 64;
        float* bufA = (float*)d_ws;
        short* w1p  = (short*)((char*)d_ws + (size_t)N * C_FEAT * sizeof(float));
        short* w2p  = w1p + K1 * C_FEAT;
        prep_w_r1<<<144, 256, 0, stream>>>(We1, We2, w1p, w2p);
        copy_f4<<<cb, 256, 0, stream>>>((const float4*)x, (float4*)bufA, n4);
        edge_mlp_r1<<<eb, 256, 0, stream>>>(x, bufA, ei, ej, ea, w1p, be1, w2p, be2, E);
        bias_copy<<<cb, 256, 0, stream>>>((const float4*)bufA, bias, (float4*)out, n4);
        edge_mlp_r1<<<eb, 256, 0, stream>>>(bufA, out, ei, ej, ea, w1p, be1, w2p, be2, E);
    }
}

// Round 5
// 668.903 us; speedup vs baseline: 1.0579x; 1.0579x over previous
//
#include <hip/hip_runtime.h>

#define C_FEAT 128
#define C_EDGE 32
#define K1 288
#define Z16S 136   // Z buffer stride (shorts): 16B-aligned rows
#define MTS 36     // M_T stride (shorts): 8B-aligned b64 ops, <=2-way banks

typedef __attribute__((ext_vector_type(8))) short bf16x8;
typedef __attribute__((ext_vector_type(4))) short bf16x4;
typedef __attribute__((ext_vector_type(4))) float f32x4;

__device__ __forceinline__ short f2bf(float x) {
    union { float f; unsigned u; } v; v.f = x;
    unsigned r = v.u + 0x7fffu + ((v.u >> 16) & 1u);   // RTN-even
    return (short)(r >> 16);
}
__device__ __forceinline__ float b2f(short s) {
    union { float f; unsigned u; } v; v.u = ((unsigned)(unsigned short)s) << 16;
    return v.f;
}
__device__ __forceinline__ bf16x8 cvt8(float4 a, float4 b) {
    bf16x8 r;
    r[0] = f2bf(a.x); r[1] = f2bf(a.y); r[2] = f2bf(a.z); r[3] = f2bf(a.w);
    r[4] = f2bf(b.x); r[5] = f2bf(b.y); r[6] = f2bf(b.z); r[7] = f2bf(b.w);
    return r;
}

// ---------------- weight packing ----------------
// B-fragment layout: wp[((k>>3)*F + f)*8 + (k&7)] -> 8 consecutive k for fixed
// f is one coalesced 16B load per lane.
__global__ void prep_w2(const float* __restrict__ We1, const float* __restrict__ We2,
                        short* __restrict__ w1abp, short* __restrict__ w1cp,
                        short* __restrict__ w2p) {
    int idx = blockIdx.x * 256 + threadIdx.x;
    if (idx < 128 * 256) {              // [W1a | W1b]: K=128, F=256
        int k = idx >> 8, f = idx & 255;
        float v = (f < 128) ? We1[k * 128 + f] : We1[(128 + k) * 128 + (f - 128)];
        w1abp[(((k >> 3) * 256 + f) << 3) + (k & 7)] = f2bf(v);
    }
    if (idx < 32 * 128) {               // W1c: K=32, F=128
        int k = idx >> 7, f = idx & 127;
        w1cp[(((k >> 3) * 128 + f) << 3) + (k & 7)] = f2bf(We1[(256 + k) * 128 + f]);
    }
    if (idx < 128 * 128) {              // We2
        int k = idx >> 7, f = idx & 127;
        w2p[(((k >> 3) * 128 + f) << 3) + (k & 7)] = f2bf(We2[k * 128 + f]);
    }
}

// ---------------- counting sort by ej ----------------
__global__ void k_hist(const int* __restrict__ ej, int* __restrict__ hist, int E) {
    int e = blockIdx.x * 256 + threadIdx.x;
    if (e < E) atomicAdd(&hist[ej[e]], 1);
}
__global__ void k_red(const int* __restrict__ hist, int* __restrict__ part, int N) {
    __shared__ int s[512];
    int t = threadIdx.x, i = blockIdx.x * 512 + t;
    s[t] = i < N ? hist[i] : 0;
    __syncthreads();
    for (int o = 256; o > 0; o >>= 1) {
        if (t < o) s[t] += s[t + o];
        __syncthreads();
    }
    if (t == 0) part[blockIdx.x] = s[0];
}
// parallel block-scan of partials (was a single-thread serial loop: ~50us!)
__global__ void k_scanpart(int* __restrict__ part, int nb) {
    __shared__ int s[512];
    int t = threadIdx.x;
    int v = t < nb ? part[t] : 0;
    s[t] = v;
    __syncthreads();
    for (int o = 1; o < 512; o <<= 1) {
        int x = (t >= o) ? s[t - o] : 0;
        __syncthreads();
        s[t] += x;
        __syncthreads();
    }
    if (t < nb) part[t] = s[t] - v;   // exclusive
}
// exclusive scan -> woff (mutated by k_perm) and rstart (preserved CSR offsets)
__global__ void k_scanblk(const int* __restrict__ hist, const int* __restrict__ part,
                          int* __restrict__ woff, int* __restrict__ rstart, int N) {
    __shared__ int s[512];
    int t = threadIdx.x, i = blockIdx.x * 512 + t;
    int v = i < N ? hist[i] : 0;
    s[t] = v;
    __syncthreads();
    for (int o = 1; o < 512; o <<= 1) {
        int x = (t >= o) ? s[t - o] : 0;
        __syncthreads();
        s[t] += x;
        __syncthreads();
    }
    if (i < N) {
        int ex = part[blockIdx.x] + s[t] - v;
        woff[i] = ex;
        rstart[i] = ex;
    }
}
// permute edges into ej-sorted order; fuse ea gather+bf16 convert.
__global__ void k_perm(const int* __restrict__ ei, const int* __restrict__ ej,
                       const float* __restrict__ ea, int* __restrict__ woff,
                       int* __restrict__ ei_s, int* __restrict__ ej_s,
                       short* __restrict__ ea_s, int E) {
    int e = blockIdx.x * 256 + threadIdx.x;
    if (e < E) {
        int t = ej[e];
        int pos = atomicAdd(&woff[t], 1);
        ei_s[pos] = ei[e];
        ej_s[pos] = t;
        const float4* src = (const float4*)(ea + (size_t)e * C_EDGE);
        short* dst = ea_s + (size_t)pos * C_EDGE;
#pragma unroll
        for (int c = 0; c < 4; ++c) {
            float4 a0 = src[2 * c], a1 = src[2 * c + 1];
            bf16x8 v = cvt8(a0, a1);
            *(bf16x8*)(dst + c * 8) = v;
        }
    }
}

// ---------------- Xab = h @ [W1a|W1b]  (N x 256, bf16) ----------------
__global__ __launch_bounds__(256) void gemm1(const float* __restrict__ h,
                                             const short* __restrict__ w1abp,
                                             short* __restrict__ Xab, int N) {
    const int tid = threadIdx.x, wave = tid >> 6, lane = tid & 63;
    const int l15 = lane & 15, q = lane >> 4;
    const int nbase = blockIdx.x * 64 + wave * 16;
    const int nr = nbase + l15;
    const int nrc = nr < N ? nr : N - 1;
    f32x4 acc[16];
#pragma unroll
    for (int nt = 0; nt < 16; ++nt) acc[nt] = (f32x4){0.f, 0.f, 0.f, 0.f};
#pragma unroll
    for (int c = 0; c < 4; ++c) {
        const float* asrc = h + (size_t)nrc * C_FEAT + c * 32 + q * 8;
        float4 a0 = ((const float4*)asrc)[0];
        float4 a1 = ((const float4*)asrc)[1];
        bf16x8 af = cvt8(a0, a1);
        const short* bb = w1abp + ((c * 4 + q) * 256) * 8;
#pragma unroll
        for (int nt = 0; nt < 16; ++nt) {
            bf16x8 bf = *(const bf16x8*)(bb + (nt * 16 + l15) * 8);
            acc[nt] = __builtin_amdgcn_mfma_f32_16x16x32_bf16(af, bf, acc[nt], 0, 0, 0);
        }
    }
#pragma unroll
    for (int rr = 0; rr < 4; ++rr) {
        int n = nbase + q * 4 + rr;
        if (n < N) {
#pragma unroll
            for (int nt = 0; nt < 16; ++nt) {
                Xab[(size_t)n * 256 + nt * 16 + l15] = f2bf(acc[nt][rr]);
            }
        }
    }
}

// ---- node-owner edge pass with MFMA segment-aggregation.
// Wave owns 16 nodes. Per 32-edge chunk: per 16-edge tile compute
// m = relu(Xa[ei]+Xb[ej]+ea@W1c+be1)@We2+be2 -> M_T[f][edge] in LDS; then
// agg += S @ M (S = 0/1 selection built from ej via shuffles). Epilogue:
// out = src + addvec + agg, one plain write per element. No atomics/barriers.
__global__ __launch_bounds__(256) void edge_agg(
    const short* __restrict__ Xab, const short* __restrict__ ea_s,
    const int* __restrict__ ei_s, const int* __restrict__ ej_s,
    const short* __restrict__ w1cp, const float* __restrict__ be1,
    const short* __restrict__ w2p, const float* __restrict__ be2,
    const int* __restrict__ rstart, const float* src,
    const float* __restrict__ addvec, float* out, int E, int N)
{
    __shared__ short Z16[4][16 * Z16S];   // per-wave z buffer (A-layout)
    __shared__ short MT[4][128 * MTS];    // per-wave transposed m chunk
    const int tid = threadIdx.x, wave = tid >> 6, lane = tid & 63;
    const int l15 = lane & 15, q = lane >> 4;
    const int n0 = (blockIdx.x * 4 + wave) * 16;
    if (n0 >= N) return;
    const int nend = (n0 + 16 < N) ? (n0 + 16) : N;
    const int s   = __builtin_amdgcn_readfirstlane(rstart[n0]);
    const int end = __builtin_amdgcn_readfirstlane((nend == N) ? E : rstart[nend]);

    short* zw = &Z16[wave][0];
    short* mt = &MT[wave][0];

    float be1v[8], b2v[8], av[8];
#pragma unroll
    for (int nt = 0; nt < 8; ++nt) {
        int f = nt * 16 + l15;
        be1v[nt] = be1[f];
        b2v[nt]  = be2[f];
        av[nt]   = addvec[f];
    }

    f32x4 aggv[8];
#pragma unroll
    for (int nt = 0; nt < 8; ++nt) aggv[nt] = (f32x4){0.f, 0.f, 0.f, 0.f};

    for (int cb = s; cb < end; cb += 32) {
        int nj2[2];
#pragma unroll
        for (int t = 0; t < 2; ++t) {
            int e = cb + t * 16 + l15;
            int ecl = e < end ? e : end - 1;
            int ni = ei_s[ecl];
            int nj = ej_s[ecl];
            nj2[t] = nj;

            // ---- z = ea @ W1c + be1 -> Z16 (A-layout [edge][f]) ----
            bf16x8 eaf = *(const bf16x8*)(ea_s + (size_t)ecl * C_EDGE + q * 8);
#pragma unroll
            for (int nt = 0; nt < 8; ++nt) {
                bf16x8 wf = *(const bf16x8*)(w1cp + ((q * C_FEAT + nt * 16 + l15) << 3));
                f32x4 z = __builtin_amdgcn_mfma_f32_16x16x32_bf16(
                    eaf, wf, (f32x4){0.f, 0.f, 0.f, 0.f}, 0, 0, 0);
                int f = nt * 16 + l15;
#pragma unroll
                for (int r = 0; r < 4; ++r)
                    zw[(q * 4 + r) * Z16S + f] = f2bf(z[r] + be1v[nt]);
            }

            // ---- layer 2: m = relu(Xa[ei]+Xb[ej]+z) @ We2 ----
            f32x4 acc[8];
#pragma unroll
            for (int nt = 0; nt < 8; ++nt) acc[nt] = (f32x4){0.f, 0.f, 0.f, 0.f};
#pragma unroll
            for (int c = 0; c < 4; ++c) {
                bf16x8 xa = *(const bf16x8*)(Xab + (size_t)ni * 256 + c * 32 + q * 8);
                bf16x8 xb = *(const bf16x8*)(Xab + (size_t)nj * 256 + 128 + c * 32 + q * 8);
                bf16x8 zz = *(const bf16x8*)(&zw[l15 * Z16S + c * 32 + q * 8]);
                bf16x8 af;
#pragma unroll
                for (int j = 0; j < 8; ++j) {
                    float z = b2f(xa[j]) + b2f(xb[j]) + b2f(zz[j]);
                    af[j] = f2bf(z > 0.f ? z : 0.f);
                }
                const short* bb = w2p + ((c * 4 + q) * C_FEAT) * 8;
#pragma unroll
                for (int nt = 0; nt < 8; ++nt) {
                    bf16x8 bf = *(const bf16x8*)(bb + (nt * 16 + l15) * 8);
                    acc[nt] = __builtin_amdgcn_mfma_f32_16x16x32_bf16(af, bf, acc[nt], 0, 0, 0);
                }
            }

            // ---- m (+be2) -> M_T[f][edge], packed 4-short (8B) writes ----
#pragma unroll
            for (int nt = 0; nt < 8; ++nt) {
                unsigned long long pk = 0;
#pragma unroll
                for (int r = 0; r < 4; ++r) {
                    unsigned short h = (unsigned short)f2bf(acc[nt][r] + b2v[nt]);
                    pk |= ((unsigned long long)h) << (16 * r);
                }
                *(unsigned long long*)(mt + (nt * 16 + l15) * MTS + t * 16 + q * 4) = pk;
            }
        }

        // ---- S-fragment from ej (sorted => targets in [n0,n0+16)) ----
        bf16x8 sf;
#pragma unroll
        for (int j = 0; j < 8; ++j) {
            int k = q * 8 + j;
            int v0 = __shfl(nj2[0], k & 15);
            int v1 = __shfl(nj2[1], k & 15);
            int v = (k < 16) ? v0 : v1;
            sf[j] = ((cb + k) < end && v == n0 + l15) ? (short)0x3F80 : (short)0;
        }
        // ---- agg += S @ M ----
#pragma unroll
        for (int nt = 0; nt < 8; ++nt) {
            const short* mp = mt + (nt * 16 + l15) * MTS + q * 8;
            bf16x4 lo = *(const bf16x4*)(mp);
            bf16x4 hi = *(const bf16x4*)(mp + 4);
            bf16x8 mb = {lo[0], lo[1], lo[2], lo[3], hi[0], hi[1], hi[2], hi[3]};
            aggv[nt] = __builtin_amdgcn_mfma_f32_16x16x32_bf16(sf, mb, aggv[nt], 0, 0, 0);
        }
    }

    // ---- epilogue: out = src + addvec + agg (each row owned exclusively) ----
#pragma unroll
    for (int r = 0; r < 4; ++r) {
        int n = n0 + q * 4 + r;
        if (n < N) {
#pragma unroll
            for (int nt = 0; nt < 8; ++nt) {
                size_t ix = (size_t)n * C_FEAT + nt * 16 + l15;
                out[ix] = src[ix] + av[nt] + aggv[nt][r];
            }
        }
    }
}

// ================= round-1 fallback path (known-good) =================
__global__ void prep_w_r1(const float* __restrict__ W1, const float* __restrict__ W2,
                          short* __restrict__ w1p, short* __restrict__ w2p) {
    int idx = blockIdx.x * 256 + threadIdx.x;
    if (idx < K1 * C_FEAT) {
        int k = idx >> 7, f = idx & 127;
        w1p[(((k >> 3) * C_FEAT + f) << 3) + (k & 7)] = f2bf(W1[idx]);
    }
    if (idx < C_FEAT * C_FEAT) {
        int k = idx >> 7, f = idx & 127;
        w2p[(((k >> 3) * C_FEAT + f) << 3) + (k & 7)] = f2bf(W2[idx]);
    }
}
__global__ void copy_f4(const float4* __restrict__ s, float4* __restrict__ d, int n4) {
    int i = blockIdx.x * 256 + threadIdx.x;
    if (i < n4) d[i] = s[i];
}
__global__ void bias_copy(const float4* __restrict__ s, const float* __restrict__ bias,
                          float4* __restrict__ d, int n4) {
    int i = blockIdx.x * 256 + threadIdx.x;
    if (i < n4) {
        float4 v = s[i];
        float4 b = ((const float4*)bias)[i & 31];
        d[i] = make_float4(v.x + b.x, v.y + b.y, v.z + b.z, v.w + b.w);
    }
}
__global__ __launch_bounds__(256) void edge_mlp_r1(
    const float* __restrict__ h, float* __restrict__ hdst,
    const int* __restrict__ ei, const int* __restrict__ ej,
    const float* __restrict__ ea,
    const short* __restrict__ w1p, const float* __restrict__ be1,
    const short* __restrict__ w2p, const float* __restrict__ be2, int E) {
    __shared__ short Hs[64][136];
    const int tid = threadIdx.x, wave = tid >> 6, lane = tid & 63;
    const int l15 = lane & 15, q = lane >> 4;
    const int ewave = blockIdx.x * 64 + wave * 16;
    const int eg = ewave + l15;
    const int egc = eg < E ? eg : E - 1;
    const int ni = ei[egc], nj = ej[egc];
    f32x4 acc[8];
#pragma unroll
    for (int nt = 0; nt < 8; ++nt) acc[nt] = (f32x4){0.f, 0.f, 0.f, 0.f};
#pragma unroll
    for (int c = 0; c < 9; ++c) {
        const float* asrc;
        if (c < 4)      asrc = h + (size_t)ni * C_FEAT + c * 32 + q * 8;
        else if (c < 8) asrc = h + (size_t)nj * C_FEAT + (c - 4) * 32 + q * 8;
        else            asrc = ea + (size_t)egc * C_EDGE + q * 8;
        float4 a0 = ((const float4*)asrc)[0];
        float4 a1 = ((const float4*)asrc)[1];
        bf16x8 af = cvt8(a0, a1);
        const short* bb = w1p + ((c * 4 + q) * C_FEAT) * 8;
#pragma unroll
        for (int nt = 0; nt < 8; ++nt) {
            bf16x8 bf = *(const bf16x8*)(bb + (nt * 16 + l15) * 8);
            acc[nt] = __builtin_amdgcn_mfma_f32_16x16x32_bf16(af, bf, acc[nt], 0, 0, 0);
        }
    }
#pragma unroll
    for (int nt = 0; nt < 8; ++nt) {
        int f = nt * 16 + l15;
        float b = be1[f];
#pragma unroll
        for (int r = 0; r < 4; ++r) {
            float v = acc[nt][r] + b;
            Hs[wave * 16 + q * 4 + r][f] = f2bf(v > 0.f ? v : 0.f);
        }
    }
    __syncthreads();
    f32x4 acc2[8];
#pragma unroll
    for (int nt = 0; nt < 8; ++nt) acc2[nt] = (f32x4){0.f, 0.f, 0.f, 0.f};
#pragma unroll
    for (int c = 0; c < 4; ++c) {
        bf16x8 af = *(const bf16x8*)(&Hs[wave * 16 + l15][c * 32 + q * 8]);
        const short* bb = w2p + ((c * 4 + q) * C_FEAT) * 8;
#pragma unroll
        for (int nt = 0; nt < 8; ++nt) {
            bf16x8 bf = *(const bf16x8*)(bb + (nt * 16 + l15) * 8);
            acc2[nt] = __builtin_amdgcn_mfma_f32_16x16x32_bf16(af, bf, acc2[nt], 0, 0, 0);
        }
    }
    float b2v[8];
#pragma unroll
    for (int nt = 0; nt < 8; ++nt) b2v[nt] = be2[nt * 16 + l15];
#pragma unroll
    for (int r = 0; r < 4; ++r) {
        int e = ewave + q * 4 + r;
        if (e < E) {
            int tn = ej[e];
            float* dst = hdst + (size_t)tn * C_FEAT;
#pragma unroll
            for (int nt = 0; nt < 8; ++nt)
                unsafeAtomicAdd(dst + nt * 16 + l15, acc2[nt][r] + b2v[nt]);
        }
    }
}

static inline size_t al256(size_t x) { return (x + 255) & ~(size_t)255; }

extern "C" void kernel_launch(void* const* d_in, const int* in_sizes, int n_in,
                              void* d_out, int out_size, void* d_ws, size_t ws_size,
                              hipStream_t stream) {
    const float* x    = (const float*)d_in[0];
    const int*   eidx = (const int*)  d_in[1];
    const float* ea   = (const float*)d_in[2];
    const float* We1  = (const float*)d_in[3];
    const float* be1  = (const float*)d_in[4];
    const float* We2  = (const float*)d_in[5];
    const float* be2  = (const float*)d_in[6];
    const float* bias = (const float*)d_in[7];
    float* out = (float*)d_out;

    const int E = in_sizes[1] / 2;
    const int N = in_sizes[0] / C_FEAT;
    const int* ei = eidx;
    const int* ej = eidx + E;

    const int n4 = N * C_FEAT / 4;
    const int cb = (n4 + 255) / 256;
    const int ngroups = (N + 15) / 16;
    const int nblocks = (ngroups + 3) / 4;

    // ---- workspace layout ----
    size_t off = 0;
    size_t o_w1abp = off; off = al256(off + (size_t)128 * 256 * 2);
    size_t o_w1cp  = off; off = al256(off + (size_t)32 * 128 * 2);
    size_t o_w2p   = off; off = al256(off + (size_t)128 * 128 * 2);
    size_t o_zero  = off; off = al256(off + (size_t)512);
    size_t o_hist  = off; off = al256(off + (size_t)N * 4);
    size_t o_part  = off; off = al256(off + (size_t)4096);
    size_t o_woff  = off; off = al256(off + (size_t)N * 4);
    size_t o_rst   = off; off = al256(off + (size_t)N * 4);
    size_t o_eis   = off; off = al256(off + (size_t)E * 4);
    size_t o_ejs   = off; off = al256(off + (size_t)E * 4);
    size_t o_eas   = off; off = al256(off + (size_t)E * C_EDGE * 2);
    size_t o_xab   = off; off = al256(off + (size_t)N * 256 * 2);
    const size_t need = off;

    if (ws_size >= need) {
        char* ws = (char*)d_ws;
        short* w1abp = (short*)(ws + o_w1abp);
        short* w1cp  = (short*)(ws + o_w1cp);
        short* w2p   = (short*)(ws + o_w2p);
        float* zerov = (float*)(ws + o_zero);
        int* hist    = (int*)(ws + o_hist);
        int* part    = (int*)(ws + o_part);
        int* woff    = (int*)(ws + o_woff);
        int* rstart  = (int*)(ws + o_rst);
        int* ei_s    = (int*)(ws + o_eis);
        int* ej_s    = (int*)(ws + o_ejs);
        short* ea_s  = (short*)(ws + o_eas);
        short* Xab   = (short*)(ws + o_xab);

        const int nbScan = (N + 511) / 512;

        prep_w2<<<128, 256, 0, stream>>>(We1, We2, w1abp, w1cp, w2p);
        hipMemsetAsync(hist, 0, (size_t)N * 4, stream);
        hipMemsetAsync(zerov, 0, 512, stream);
        // counting sort by ej (+ fused ea permute/convert) + CSR offsets
        k_hist<<<(E + 255) / 256, 256, 0, stream>>>(ej, hist, E);
        k_red<<<nbScan, 512, 0, stream>>>(hist, part, N);
        k_scanpart<<<1, 512, 0, stream>>>(part, nbScan);
        k_scanblk<<<nbScan, 512, 0, stream>>>(hist, part, woff, rstart, N);
        k_perm<<<(E + 255) / 256, 256, 0, stream>>>(ei, ej, ea, woff, ei_s, ej_s, ea_s, E);

        // step 1: out = x + agg(m1)
        gemm1<<<(N + 63) / 64, 256, 0, stream>>>(x, w1abp, Xab, N);
        edge_agg<<<nblocks, 256, 0, stream>>>(Xab, ea_s, ei_s, ej_s, w1cp, be1,
                                              w2p, be2, rstart, x, zerov, out, E, N);
        // step 2: out = h1 + bias + agg(m2)
        gemm1<<<(N + 63) / 64, 256, 0, stream>>>(out, w1abp, Xab, N);
        edge_agg<<<nblocks, 256, 0, stream>>>(Xab, ea_s, ei_s, ej_s, w1cp, be1,
                                              w2p, be2, rstart, out, bias, out, E, N);
    } else {
        // round-1 known-good fallback
        const int eb = (E + 63) / 64;
        float* bufA = (float*)d_ws;
        short* w1p  = (short*)((char*)d_ws + (size_t)N * C_FEAT * sizeof(float));
        short* w2p  = w1p + K1 * C_FEAT;
        prep_w_r1<<<144, 256, 0, stream>>>(We1, We2, w1p, w2p);
        copy_f4<<<cb, 256, 0, stream>>>((const float4*)x, (float4*)bufA, n4);
        edge_mlp_r1<<<eb, 256, 0, stream>>>(x, bufA, ei, ej, ea, w1p, be1, w2p, be2, E);
        bias_copy<<<cb, 256, 0, stream>>>((const float4*)bufA, bias, (float4*)out, n4);
        edge_mlp_r1<<<eb, 256, 0, stream>>>(bufA, out, ei, ej, ea, w1p, be1, w2p, be2, E);
    }
}